// Round 2
// baseline (55.254 us; speedup 1.0000x reference)
//
#include <hip/hip_runtime.h>
#include <math.h>

// LightingProbes: N points, 5x5x5 probe grid on [-3,3] (h=1.5), K=4 nearest,
// cubemaps (125,6,16,16,3) f32. One thread per point.
//
// R2: cubemap repacked to float4 (padded) in d_ws -> bilinear gather is
// 16x global_load_dwordx4 instead of 48 scalar dwords (L1 line-lookup bound).
// All divisions -> v_rcp_f32 (continuous math only). Selection loop kept
// bit-identical to R1 (verified top-4 tie behavior).

#define GRID_LO  -3.0f
#define GRID_H    1.5f
#define NTEX     192000   // 125*6*16*16 texels

__device__ __forceinline__ float fastrcp(float x) { return __builtin_amdgcn_rcpf(x); }

__device__ __forceinline__ int dim_start(float v) {
    float f = (v + 3.0f) * (1.0f / 1.5f);
    int n = (int)floorf(f + 0.5f);
    n = n < 0 ? 0 : (n > 4 ? 4 : n);
    int s = n - 1;
    s = s < 0 ? 0 : (s > 2 ? 2 : s);
    return s;
}

// Shared per-point computation: top-4 probes, weights, face/uv/bilinear.
__device__ __forceinline__ void setup_point(
    float x, float y, float z, float dx, float dy, float dz,
    int& i0, int& i1, int& i2, int& i3,
    float& w0, float& w1, float& w2, float& w3,
    int& face, int& t00, int& t01, int& t10, int& t11,
    float& w00, float& w01, float& w10, float& w11)
{
    // ---- top-4 probe selection over 27 grid candidates (bit-identical to R1) ----
    float x2 = fmaf(x, x, fmaf(y, y, z * z));
    int sx = dim_start(x), sy = dim_start(y), sz = dim_start(z);

    float d0v = 1e30f, d1v = 1e30f, d2v = 1e30f, d3v = 1e30f;
    i0 = 0; i1 = 0; i2 = 0; i3 = 0;

#pragma unroll
    for (int a = 0; a < 3; a++) {
        const int ixg = sx + a;
        const float px = GRID_LO + GRID_H * (float)ixg;
#pragma unroll
        for (int b = 0; b < 3; b++) {
            const int iyg = sy + b;
            const float py = GRID_LO + GRID_H * (float)iyg;
#pragma unroll
            for (int c = 0; c < 3; c++) {
                const int izg = sz + c;
                const float pz = GRID_LO + GRID_H * (float)izg;

                float dot = fmaf(x, px, fmaf(y, py, z * pz));
                float p2  = fmaf(px, px, fmaf(py, py, pz * pz));
                float dd  = fmaf(-2.0f, dot, x2 + p2);
                dd = fmaxf(dd, 0.0f);
                float dist = sqrtf(dd);
                int idx = (ixg * 5 + iyg) * 5 + izg;

                {
                    bool lt = dist < d3v;
                    d3v = lt ? dist : d3v; i3 = lt ? idx : i3;
                }
                {
                    bool cb = d3v < d2v;
                    float nd2 = cb ? d3v : d2v, nd3 = cb ? d2v : d3v;
                    int   ni2 = cb ? i3 : i2,   ni3 = cb ? i2 : i3;
                    d2v = nd2; d3v = nd3; i2 = ni2; i3 = ni3;
                }
                {
                    bool cb = d2v < d1v;
                    float nd1 = cb ? d2v : d1v, nd2 = cb ? d1v : d2v;
                    int   ni1 = cb ? i2 : i1,   ni2 = cb ? i1 : i2;
                    d1v = nd1; d2v = nd2; i1 = ni1; i2 = ni2;
                }
                {
                    bool cb = d1v < d0v;
                    float nd0 = cb ? d1v : d0v, nd1 = cb ? d0v : d1v;
                    int   ni0 = cb ? i1 : i0,   ni1 = cb ? i0 : i1;
                    d0v = nd0; d1v = nd1; i0 = ni0; i1 = ni1;
                }
            }
        }
    }

    // ---- weights (rcp approx: continuous) ----
    w0 = fastrcp(d0v + 1e-4f);
    w1 = fastrcp(d1v + 1e-4f);
    w2 = fastrcp(d2v + 1e-4f);
    w3 = fastrcp(d3v + 1e-4f);
    float winv = fastrcp(w0 + w1 + w2 + w3);
    w0 *= winv; w1 *= winv; w2 *= winv; w3 *= winv;

    // ---- direction -> face, uv ----
    float nrm = sqrtf(fmaf(dx, dx, fmaf(dy, dy, dz * dz)));
    nrm = fmaxf(nrm, 1e-12f);
    float inv = fastrcp(nrm);
    float ux = dx * inv, uy = dy * inv, uz = dz * inv;
    float ax = fabsf(ux), ay = fabsf(uy), az = fabsf(uz);

    bool xd = (ax >= ay) && (ax >= az);
    float den, un, vn;
    if (xd) {
        face = (ux > 0.0f) ? 0 : 1;
        den = ax;
        un = (ux > 0.0f) ? -uz : uz;
        vn = -uy;
    } else if (ay >= az) {
        face = (uy > 0.0f) ? 2 : 3;
        den = ay;
        un = ux;
        vn = (uy > 0.0f) ? uz : -uz;
    } else {
        face = (uz > 0.0f) ? 4 : 5;
        den = az;
        un = (uz > 0.0f) ? ux : -ux;
        vn = -uy;
    }
    float rden = fastrcp(den + 1e-8f);
    float u = un * rden;
    float v = vn * rden;
    u = fminf(1.0f, fmaxf(-1.0f, u));
    v = fminf(1.0f, fmaxf(-1.0f, v));

    // ---- bilinear coords (W=H=16) ----
    float fx = (u + 1.0f) * 0.5f * 15.0f;
    float fy = (v + 1.0f) * 0.5f * 15.0f;
    float x0f = floorf(fx), y0f = floorf(fy);
    float wx = fx - x0f, wy = fy - y0f;
    int px0 = (int)x0f; px0 = px0 < 0 ? 0 : (px0 > 15 ? 15 : px0);
    int py0 = (int)y0f; py0 = py0 < 0 ? 0 : (py0 > 15 ? 15 : py0);
    int px1 = px0 + 1 > 15 ? 15 : px0 + 1;
    int py1 = py0 + 1 > 15 ? 15 : py0 + 1;

    w00 = (1.0f - wx) * (1.0f - wy);
    w01 = wx * (1.0f - wy);
    w10 = (1.0f - wx) * wy;
    w11 = wx * wy;

    t00 = py0 * 16 + px0;
    t01 = py0 * 16 + px1;
    t10 = py1 * 16 + px0;
    t11 = py1 * 16 + px1;
}

// ---- repack cubemap (125,6,16,16,3) f32 -> float4-padded texels in ws ----
__global__ __launch_bounds__(256) void repack_kernel(
    const float* __restrict__ cube, float4* __restrict__ cube4)
{
    int t = blockIdx.x * blockDim.x + threadIdx.x;
    if (t >= NTEX) return;
    float4 v;
    v.x = cube[3 * t + 0];
    v.y = cube[3 * t + 1];
    v.z = cube[3 * t + 2];
    v.w = 0.0f;
    cube4[t] = v;
}

// ---- main kernel, packed-float4 gather path ----
__global__ __launch_bounds__(256) void lighting_probes_packed(
    const float* __restrict__ xyz,
    const float* __restrict__ vdirs,
    const float4* __restrict__ cube4,
    float* __restrict__ out,
    int N)
{
    int i = blockIdx.x * blockDim.x + threadIdx.x;
    if (i >= N) return;

    float x = __builtin_nontemporal_load(&xyz[3 * i + 0]);
    float y = __builtin_nontemporal_load(&xyz[3 * i + 1]);
    float z = __builtin_nontemporal_load(&xyz[3 * i + 2]);
    float dx = __builtin_nontemporal_load(&vdirs[3 * i + 0]);
    float dy = __builtin_nontemporal_load(&vdirs[3 * i + 1]);
    float dz = __builtin_nontemporal_load(&vdirs[3 * i + 2]);

    int i0, i1, i2, i3, face, t00, t01, t10, t11;
    float w0, w1, w2, w3, w00, w01, w10, w11;
    setup_point(x, y, z, dx, dy, dz, i0, i1, i2, i3, w0, w1, w2, w3,
                face, t00, t01, t10, t11, w00, w01, w10, w11);

    int faceoff = face * 256;          // texel units; 6*256=1536 per probe
    float accr = 0.0f, accg = 0.0f, accb = 0.0f;
#pragma unroll
    for (int k = 0; k < 4; k++) {
        int   p  = (k == 0) ? i0 : (k == 1) ? i1 : (k == 2) ? i2 : i3;
        float wn = (k == 0) ? w0 : (k == 1) ? w1 : (k == 2) ? w2 : w3;
        int base = p * 1536 + faceoff;
        float4 v00 = cube4[base + t00];
        float4 v01 = cube4[base + t01];
        float4 v10 = cube4[base + t10];
        float4 v11 = cube4[base + t11];
        float r = fmaf(v00.x, w00, fmaf(v01.x, w01, fmaf(v10.x, w10, v11.x * w11)));
        float g = fmaf(v00.y, w00, fmaf(v01.y, w01, fmaf(v10.y, w10, v11.y * w11)));
        float b = fmaf(v00.z, w00, fmaf(v01.z, w01, fmaf(v10.z, w10, v11.z * w11)));
        accr = fmaf(wn, r, accr);
        accg = fmaf(wn, g, accg);
        accb = fmaf(wn, b, accb);
    }

    __builtin_nontemporal_store(accr, &out[3 * i + 0]);
    __builtin_nontemporal_store(accg, &out[3 * i + 1]);
    __builtin_nontemporal_store(accb, &out[3 * i + 2]);
}

// ---- fallback: direct scalar gather (R1 behavior) if ws too small ----
__global__ __launch_bounds__(256) void lighting_probes_scalar(
    const float* __restrict__ xyz,
    const float* __restrict__ vdirs,
    const float* __restrict__ cube,
    float* __restrict__ out,
    int N)
{
    int i = blockIdx.x * blockDim.x + threadIdx.x;
    if (i >= N) return;

    float x = __builtin_nontemporal_load(&xyz[3 * i + 0]);
    float y = __builtin_nontemporal_load(&xyz[3 * i + 1]);
    float z = __builtin_nontemporal_load(&xyz[3 * i + 2]);
    float dx = __builtin_nontemporal_load(&vdirs[3 * i + 0]);
    float dy = __builtin_nontemporal_load(&vdirs[3 * i + 1]);
    float dz = __builtin_nontemporal_load(&vdirs[3 * i + 2]);

    int i0, i1, i2, i3, face, t00, t01, t10, t11;
    float w0, w1, w2, w3, w00, w01, w10, w11;
    setup_point(x, y, z, dx, dy, dz, i0, i1, i2, i3, w0, w1, w2, w3,
                face, t00, t01, t10, t11, w00, w01, w10, w11);

    int faceoff = face * 768;
    int c00 = t00 * 3, c01 = t01 * 3, c10 = t10 * 3, c11 = t11 * 3;
    float accr = 0.0f, accg = 0.0f, accb = 0.0f;
#pragma unroll
    for (int k = 0; k < 4; k++) {
        int   p  = (k == 0) ? i0 : (k == 1) ? i1 : (k == 2) ? i2 : i3;
        float wn = (k == 0) ? w0 : (k == 1) ? w1 : (k == 2) ? w2 : w3;
        int base = p * 4608 + faceoff;
        int o00 = base + c00, o01 = base + c01, o10 = base + c10, o11 = base + c11;
#pragma unroll
        for (int ch = 0; ch < 3; ch++) {
            float v00 = cube[o00 + ch];
            float v01 = cube[o01 + ch];
            float v10 = cube[o10 + ch];
            float v11 = cube[o11 + ch];
            float val = fmaf(v00, w00, fmaf(v01, w01, fmaf(v10, w10, v11 * w11)));
            if (ch == 0) accr = fmaf(wn, val, accr);
            else if (ch == 1) accg = fmaf(wn, val, accg);
            else accb = fmaf(wn, val, accb);
        }
    }

    __builtin_nontemporal_store(accr, &out[3 * i + 0]);
    __builtin_nontemporal_store(accg, &out[3 * i + 1]);
    __builtin_nontemporal_store(accb, &out[3 * i + 2]);
}

extern "C" void kernel_launch(void* const* d_in, const int* in_sizes, int n_in,
                              void* d_out, int out_size, void* d_ws, size_t ws_size,
                              hipStream_t stream) {
    const float* xyz  = (const float*)d_in[0];
    const float* vd   = (const float*)d_in[1];
    const float* cube = (const float*)d_in[2];
    float* outp = (float*)d_out;
    int N = in_sizes[0] / 3;
    int blocks = (N + 255) / 256;

    if (ws_size >= (size_t)NTEX * sizeof(float4)) {
        float4* cube4 = (float4*)d_ws;
        hipLaunchKernelGGL(repack_kernel, dim3((NTEX + 255) / 256), dim3(256), 0, stream,
                           cube, cube4);
        hipLaunchKernelGGL(lighting_probes_packed, dim3(blocks), dim3(256), 0, stream,
                           xyz, vd, cube4, outp, N);
    } else {
        hipLaunchKernelGGL(lighting_probes_scalar, dim3(blocks), dim3(256), 0, stream,
                           xyz, vd, cube, outp, N);
    }
}